// Round 1
// baseline (302.390 us; speedup 1.0000x reference)
//
#include <hip/hip_runtime.h>

#define NBINS 10
#define INV 0.1f   // == float(1.0/10), matches reference's inv in f32
#define U 16       // staging depth per buffer; A/B double-buffer => 32 loads
                   // in flight during every consume phase (vmcnt window is 63)

__device__ __forceinline__ void update_state(float& lo, float& hi, float cap,
                                             bool succ, bool fail) {
    // success branch: if cap > hi: hi = cap; elif cap > lo: lo = cap
    float s_hi = (cap > hi) ? cap : hi;
    float s_lo = ((cap <= hi) && (cap > lo)) ? cap : lo;
    // failure branch: if cap < lo: lo = cap; elif cap < hi: hi = cap
    float f_lo = (cap < lo) ? cap : lo;
    float f_hi = ((cap >= lo) && (cap < hi)) ? cap : hi;
    float lo2 = succ ? s_lo : (fail ? f_lo : lo);
    float hi2 = succ ? s_hi : (fail ? f_hi : hi);
    // degenerate-interval fixup
    bool eq = (lo2 == hi2);
    hi = (eq && (hi2 == 0.0f)) ? INV : hi2;
    lo = (eq && (hi2 != 0.0f)) ? (hi2 - INV) : lo2;
}

// Stage one batch: perf goes through the cache (the other half-block re-reads
// the same lines -> L1/L2 hit, HBM perf traffic stays ~32 MiB); caps are
// single-use streams -> nontemporal.
__device__ __forceinline__ void stage(long long (&pv)[U], float (&cv)[U],
                                      const long long* __restrict__ perf,
                                      const float* __restrict__ cap,
                                      int t0, int N, int n)
{
    #pragma unroll
    for (int u = 0; u < U; ++u) {
        size_t idx = (size_t)(t0 + u) * (size_t)N + (size_t)n;
        pv[u] = perf[idx];
        cv[u] = __builtin_nontemporal_load(&cap[idx]);
    }
}

__device__ __forceinline__ void consume(const long long (&pv)[U], const float (&cv)[U],
                                        float& lo, float& hi)
{
    #pragma unroll
    for (int u = 0; u < U; ++u) {
        bool s0 = ((int)(pv[u] & 0xffffffffLL)) != 0;            // fail bit (low word)
        bool s1 = ((int)((unsigned long long)pv[u] >> 32)) != 0; // success bit (high word)
        update_state(lo, hi, cv[u], (!s0) && s1, s0 && (!s1));
    }
}

// Channel-split: 128 n's per block; tid<128 -> sens channel, tid>=128 -> proc
// channel (wave-uniform split, no divergence). 2x wave count vs 1-thread-per-n:
// N=65536 -> 2048 waves -> 8 waves/CU -> 2 waves/SIMD.
__global__ __launch_bounds__(256, 2) void trust_kernel(
    const long long* __restrict__ perf,   // [T,N] packed (fail,success) as i64
    const float* __restrict__ obs_sens,   // [T,N]
    const float* __restrict__ obs_proc,   // [T,N]
    const float* __restrict__ pred_sens,  // [N]
    const float* __restrict__ pred_proc,  // [N]
    const float* __restrict__ betas,      // [2]
    const float* __restrict__ zetas,      // [2]
    float*       __restrict__ out,        // [N]
    int N, int T)
{
    const int tid = threadIdx.x;
    const int h   = tid >> 7;        // channel: 0 = sens, 1 = proc (wave-uniform)
    const int ln  = tid & 127;
    const int n   = blockIdx.x * 128 + ln;
    const bool valid = (n < N);
    const int nc  = valid ? n : (N - 1);   // clamp: safe loads, store guarded

    const float* __restrict__ cap = h ? obs_proc : obs_sens;

    float lo = 0.0f, hi = 1.0f;

    long long pA[U], pB[U];
    float     cA[U], cB[U];

    // Software-pipelined A/B scan: while consuming one buffer, the other
    // buffer's 2*U loads are in flight -> HBM never idles, latency hidden
    // by both the pipeline and 2-waves/SIMD TLP.
    int t = 0;
    const int TM = (T / (2 * U)) * (2 * U);
    if (TM >= 2 * U) {
        stage(pA, cA, perf, cap, 0, N, nc);
        stage(pB, cB, perf, cap, U, N, nc);
        while (true) {
            consume(pA, cA, lo, hi);
            if (t + 2 * U < TM) stage(pA, cA, perf, cap, t + 2 * U, N, nc);
            consume(pB, cB, lo, hi);
            if (t + 3 * U < TM) stage(pB, cB, perf, cap, t + 3 * U, N, nc);
            t += 2 * U;
            if (t >= TM) break;
        }
    }
    for (; t < T; ++t) {   // generic tail (T not a multiple of 2*U)
        size_t idx = (size_t)t * (size_t)N + (size_t)nc;
        long long pv = perf[idx];
        float cv = cap[idx];
        bool s0 = ((int)(pv & 0xffffffffLL)) != 0;
        bool s1 = ((int)((unsigned long long)pv >> 32)) != 0;
        update_state(lo, hi, cv, (!s0) && s1, s0 && (!s1));
    }

    // ---- epilogue: this thread's channel factor sum_k d[k]*m[k] / sum_k m[k] ----
    float beta = betas[h];
    float z    = zetas[h];
    float e    = -(z * z);
    float r    = h ? pred_proc[nc] : pred_sens[nc];

    float sm = 0.0f, sd = 0.0f;
    #pragma unroll
    for (int k = 0; k < NBINS; ++k) {
        float s = ((float)k + 0.5f) * INV;   // same arithmetic as reference steps
        if (s >= lo && s <= hi) {
            float p = beta * (r - s);
            sd += powf(1.0f + expf(p), e);
            sm += 1.0f;
        }
    }
    float v = sd / sm;

    // combine the two channel factors via LDS (512 B)
    __shared__ float red[128];
    if (h) red[ln] = v;
    __syncthreads();
    if (!h && valid) out[n] = v * red[ln];
}

extern "C" void kernel_launch(void* const* d_in, const int* in_sizes, int n_in,
                              void* d_out, int out_size, void* d_ws, size_t ws_size,
                              hipStream_t stream) {
    // setup_inputs order:
    // 0 inptasksobs (unused)  1 inptasksperf [T,N,2] int32  2 inptaskspred (unused)
    // 3 num_obs_tasks [N]     4 tasksobsids (unused)        5 taskspredids (unused)
    // 6 obs_task_sens_cap_seq [T,N]  7 pred_task_sens_cap [N,1]
    // 8 obs_task_proc_cap_seq [T,N]  9 pred_task_proc_cap [N,1]
    // 10 betas [2]            11 zetas [2]
    const long long* perf   = (const long long*)d_in[1];
    const float* obs_sens   = (const float*)d_in[6];
    const float* pred_sens  = (const float*)d_in[7];
    const float* obs_proc   = (const float*)d_in[8];
    const float* pred_proc  = (const float*)d_in[9];
    const float* betas      = (const float*)d_in[10];
    const float* zetas      = (const float*)d_in[11];

    int N = in_sizes[3];            // num_obs_tasks has N elements
    int T = in_sizes[6] / N;        // obs_task_sens_cap_seq is [T,N]

    int block = 256;                // 128 n's/block, 2 channels
    int grid  = (N + 127) / 128;
    trust_kernel<<<grid, block, 0, stream>>>(
        perf, obs_sens, obs_proc, pred_sens, pred_proc,
        betas, zetas, (float*)d_out, N, T);
}